// Round 15
// baseline (248.163 us; speedup 1.0000x reference)
//
#include <hip/hip_runtime.h>
#include <math.h>

// RPNLayer: logits = x(32768,1024) @ W(1024,16) + b; per-anchor (8) 2-class
// log-softmax CE over valid anchors; argmax + candidate mask.
//
// R10c: W residency forced via 64 SCALAR floats pinned INSIDE the loop.
//   R14 compile error: "+v" cannot tie aggregate (float4) operands ->
//   scalars only. R9 lesson: a pre-loop pin doesn't prevent in-loop
//   rematerialization (const memory) -> pin must be per-iteration; "+v"
//   makes the asm read-write so W cannot be re-loaded from memory after it.
//   VERDICT: VGPR_Count >=100 & WRITE_SIZE ~2.3MB -> W resident, the
//   contiguous-x hypothesis finally runs. WRITE_SIZE balloon -> spills.
//   - Block 256 thr = 4 waves; wave s covers k=[s*256,(s+1)*256) of the
//     block's 32 rows; lane l owns k = s*256+4l..+3 (64 W floats, fixed).
//   - Block x stream = 32 rows x 4KB walked linearly = 128KB contiguous;
//     each wave instr reads 1KB contiguous (16 lines).
//   - Per row: 1 float4 load + 64 FMA + channel-halving fold (17 shfl) ->
//     lane 4c holds logit(row, ch c); one ds_write per 4 lanes.
//   - In-block epilogue + ticketed loss finalize (proven R7/R8/R9).
//
// d_out (float32): [0] loss | [1..262144] predict | [262145..524288] mask
// ws: [0]=loss sum [1]=count [2]=ticket [3]=pad

#define RPB 32               // rows per block

#define PIN8(a,b,c,d,e,f,g,h)                                          \
    asm volatile("" : "+v"(a), "+v"(b), "+v"(c), "+v"(d),              \
                      "+v"(e), "+v"(f), "+v"(g), "+v"(h))

#define MULRND(sc, P)  do {                                            \
    acc0  = (sc)*P##0;  acc1  = (sc)*P##1;  acc2  = (sc)*P##2;         \
    acc3  = (sc)*P##3;  acc4  = (sc)*P##4;  acc5  = (sc)*P##5;         \
    acc6  = (sc)*P##6;  acc7  = (sc)*P##7;  acc8  = (sc)*P##8;         \
    acc9  = (sc)*P##9;  acc10 = (sc)*P##10; acc11 = (sc)*P##11;        \
    acc12 = (sc)*P##12; acc13 = (sc)*P##13; acc14 = (sc)*P##14;        \
    acc15 = (sc)*P##15; } while (0)

#define FMARND(sc, P)  do {                                            \
    acc0  = fmaf((sc), P##0,  acc0);  acc1  = fmaf((sc), P##1,  acc1); \
    acc2  = fmaf((sc), P##2,  acc2);  acc3  = fmaf((sc), P##3,  acc3); \
    acc4  = fmaf((sc), P##4,  acc4);  acc5  = fmaf((sc), P##5,  acc5); \
    acc6  = fmaf((sc), P##6,  acc6);  acc7  = fmaf((sc), P##7,  acc7); \
    acc8  = fmaf((sc), P##8,  acc8);  acc9  = fmaf((sc), P##9,  acc9); \
    acc10 = fmaf((sc), P##10, acc10); acc11 = fmaf((sc), P##11, acc11);\
    acc12 = fmaf((sc), P##12, acc12); acc13 = fmaf((sc), P##13, acc13);\
    acc14 = fmaf((sc), P##14, acc14); acc15 = fmaf((sc), P##15, acc15);\
    } while (0)

__global__ __launch_bounds__(256, 1)
void rpn_main(const float* __restrict__ x, const float* __restrict__ W,
              const float* __restrict__ b, const int* __restrict__ lab,
              float* __restrict__ out, float* __restrict__ ws)
{
    __shared__ float red[4 * RPB * 16];      // 8192 B: [slice][row][ch]
    __shared__ float rsum[8];

    const int tid  = threadIdx.x;
    const int lane = tid & 63;
    const int s    = __builtin_amdgcn_readfirstlane(tid >> 6);  // k-slice
    const int row0 = blockIdx.x * RPB;

    // ---- one-time W panel load: k = s*256 + 4*lane + j, 16 ch each ----
    const float* wp = W + (size_t)(s * 256 + lane * 4) * 16;
    float4 q0, q1, q2, q3;
    // j = 0
    q0 = *(const float4*)(wp +  0); q1 = *(const float4*)(wp +  4);
    q2 = *(const float4*)(wp +  8); q3 = *(const float4*)(wp + 12);
    float wA0=q0.x, wA1=q0.y, wA2=q0.z,  wA3=q0.w,
          wA4=q1.x, wA5=q1.y, wA6=q1.z,  wA7=q1.w,
          wA8=q2.x, wA9=q2.y, wA10=q2.z, wA11=q2.w,
          wA12=q3.x, wA13=q3.y, wA14=q3.z, wA15=q3.w;
    // j = 1
    q0 = *(const float4*)(wp + 16); q1 = *(const float4*)(wp + 20);
    q2 = *(const float4*)(wp + 24); q3 = *(const float4*)(wp + 28);
    float wB0=q0.x, wB1=q0.y, wB2=q0.z,  wB3=q0.w,
          wB4=q1.x, wB5=q1.y, wB6=q1.z,  wB7=q1.w,
          wB8=q2.x, wB9=q2.y, wB10=q2.z, wB11=q2.w,
          wB12=q3.x, wB13=q3.y, wB14=q3.z, wB15=q3.w;
    // j = 2
    q0 = *(const float4*)(wp + 32); q1 = *(const float4*)(wp + 36);
    q2 = *(const float4*)(wp + 40); q3 = *(const float4*)(wp + 44);
    float wC0=q0.x, wC1=q0.y, wC2=q0.z,  wC3=q0.w,
          wC4=q1.x, wC5=q1.y, wC6=q1.z,  wC7=q1.w,
          wC8=q2.x, wC9=q2.y, wC10=q2.z, wC11=q2.w,
          wC12=q3.x, wC13=q3.y, wC14=q3.z, wC15=q3.w;
    // j = 3
    q0 = *(const float4*)(wp + 48); q1 = *(const float4*)(wp + 52);
    q2 = *(const float4*)(wp + 56); q3 = *(const float4*)(wp + 60);
    float wD0=q0.x, wD1=q0.y, wD2=q0.z,  wD3=q0.w,
          wD4=q1.x, wD5=q1.y, wD6=q1.z,  wD7=q1.w,
          wD8=q2.x, wD9=q2.y, wD10=q2.z, wD11=q2.w,
          wD12=q3.x, wD13=q3.y, wD14=q3.z, wD15=q3.w;

    const float* xp = x + (size_t)row0 * 1024 + s * 256 + lane * 4;

    // 4-deep row prefetch (named regs; rotation collapses under unroll 4)
    float4 p0 = *(const float4*)(xp);
    float4 p1 = *(const float4*)(xp + 1024);
    float4 p2 = *(const float4*)(xp + 2048);
    float4 p3 = *(const float4*)(xp + 3072);

#pragma unroll 4
    for (int r = 0; r < RPB; ++r) {
        // per-iteration pins: "+v" is read-write -> compiler cannot
        // rematerialize W from memory; residency forced (zero insts).
        PIN8(wA0,wA1,wA2,wA3,wA4,wA5,wA6,wA7);
        PIN8(wA8,wA9,wA10,wA11,wA12,wA13,wA14,wA15);
        PIN8(wB0,wB1,wB2,wB3,wB4,wB5,wB6,wB7);
        PIN8(wB8,wB9,wB10,wB11,wB12,wB13,wB14,wB15);
        PIN8(wC0,wC1,wC2,wC3,wC4,wC5,wC6,wC7);
        PIN8(wC8,wC9,wC10,wC11,wC12,wC13,wC14,wC15);
        PIN8(wD0,wD1,wD2,wD3,wD4,wD5,wD6,wD7);
        PIN8(wD8,wD9,wD10,wD11,wD12,wD13,wD14,wD15);

        float4 xv = p0;
        p0 = p1; p1 = p2; p2 = p3;
        if (r + 4 < RPB) p3 = *(const float4*)(xp + (size_t)(r + 4) * 1024);

        const float xs0 = xv.x, xs1 = xv.y, xs2 = xv.z, xs3 = xv.w;
        float acc0, acc1, acc2,  acc3,  acc4,  acc5,  acc6,  acc7,
              acc8, acc9, acc10, acc11, acc12, acc13, acc14, acc15;
        MULRND(xs0, wA);
        FMARND(xs1, wB);
        FMARND(xs2, wC);
        FMARND(xs3, wD);

        const float acc[16] = { acc0, acc1, acc2,  acc3,
                                acc4, acc5, acc6,  acc7,
                                acc8, acc9, acc10, acc11,
                                acc12, acc13, acc14, acc15 };

        // ---- channel-halving fold: ch bit3..0 <- lane bit5..2 ----
        const bool h5 = (lane & 32) != 0;
        float k8[8];
#pragma unroll
        for (int c = 0; c < 8; ++c) {
            float keep = h5 ? acc[c + 8] : acc[c];
            float send = h5 ? acc[c]     : acc[c + 8];
            k8[c] = keep + __shfl_xor(send, 32, 64);
        }
        const bool h4 = (lane & 16) != 0;
        float k4[4];
#pragma unroll
        for (int c = 0; c < 4; ++c) {
            float keep = h4 ? k8[c + 4] : k8[c];
            float send = h4 ? k8[c]     : k8[c + 4];
            k4[c] = keep + __shfl_xor(send, 16, 64);
        }
        const bool h3 = (lane & 8) != 0;
        float k2[2];
#pragma unroll
        for (int c = 0; c < 2; ++c) {
            float keep = h3 ? k4[c + 2] : k4[c];
            float send = h3 ? k4[c]     : k4[c + 2];
            k2[c] = keep + __shfl_xor(send, 8, 64);
        }
        const bool h2 = (lane & 4) != 0;
        float keep1 = h2 ? k2[1] : k2[0];
        float send1 = h2 ? k2[0] : k2[1];
        float k1 = keep1 + __shfl_xor(send1, 4, 64);
        k1 += __shfl_xor(k1, 2, 64);         // merge k sub-groups
        k1 += __shfl_xor(k1, 1, 64);

        if ((lane & 3) == 0)
            red[(s * RPB + r) * 16 + (lane >> 2)] = k1;
    }

    __syncthreads();

    // ---- in-block epilogue: thread t -> (row = t>>3, anchor = t&7) ----
    {
        const int row = tid >> 3;
        const int a   = tid & 7;
        const int gr  = row0 + row;

        const int i0 = row * 16 + 2 * a;
        float l0 = red[0 * RPB * 16 + i0]     + red[1 * RPB * 16 + i0]
                 + red[2 * RPB * 16 + i0]     + red[3 * RPB * 16 + i0]
                 + b[2 * a];
        float l1 = red[0 * RPB * 16 + i0 + 1] + red[1 * RPB * 16 + i0 + 1]
                 + red[2 * RPB * 16 + i0 + 1] + red[3 * RPB * 16 + i0 + 1]
                 + b[2 * a + 1];

        const int lb    = lab[(size_t)gr * 8 + a];
        const int pred  = (l1 > l0) ? 1 : 0;      // strict: tie -> class 0
        const int valid = (lb != -1);
        const float m   = fmaxf(l0, l1);
        const float lse = m + logf(expf(l0 - m) + expf(l1 - m));
        const float nll = lse - ((lb == 1) ? l1 : l0);
        float lsum = valid ? nll : 0.f;
        float lcnt = valid ? 1.f : 0.f;

        out[1 + (size_t)row0 * 8 + tid]          = (float)pred;
        out[1 + 262144 + (size_t)row0 * 8 + tid] = (pred && valid) ? 1.f : 0.f;

#pragma unroll
        for (int off = 32; off > 0; off >>= 1) {
            lsum += __shfl_down(lsum, off, 64);
            lcnt += __shfl_down(lcnt, off, 64);
        }
        if (lane == 0) {
            rsum[s * 2]     = lsum;
            rsum[s * 2 + 1] = lcnt;
        }
    }
    __syncthreads();

    if (tid == 0) {
        float S = rsum[0] + rsum[2] + rsum[4] + rsum[6];
        float C = rsum[1] + rsum[3] + rsum[5] + rsum[7];
        atomicAdd(&ws[0], S);
        atomicAdd(&ws[1], C);
        __threadfence();
        unsigned int old = atomicAdd((unsigned int*)(ws + 2), 1u);
        if (old == gridDim.x - 1) {              // last block finalizes loss
            float Sf = atomicAdd(&ws[0], 0.f);
            float Cf = atomicAdd(&ws[1], 0.f);
            out[0] = Sf / fmaxf(Cf, 1.f);
        }
    }
}

extern "C" void kernel_launch(void* const* d_in, const int* in_sizes, int n_in,
                              void* d_out, int out_size, void* d_ws, size_t ws_size,
                              hipStream_t stream)
{
    const float* x   = (const float*)d_in[0];   // (64,512,1024) f32
    const float* W   = (const float*)d_in[1];   // (1024,16) f32
    const float* b   = (const float*)d_in[2];   // (16,) f32
    const int*   lab = (const int*)d_in[3];     // (64,512,8) i32 in {-1,0,1}
    float* out = (float*)d_out;
    float* ws  = (float*)d_ws;

    (void)hipMemsetAsync(ws, 0, 16, stream);
    rpn_main<<<dim3(1024), dim3(256), 0, stream>>>(x, W, b, lab, out, ws);
}